// Round 1
// baseline (313.660 us; speedup 1.0000x reference)
//
#include <hip/hip_runtime.h>
#include <hip/hip_bf16.h>
#include <stdint.h>

#define K_DIM 4096
#define N_DIM 8192

typedef __attribute__((ext_vector_type(8))) __bf16 bf16x8;
typedef __attribute__((ext_vector_type(4))) float f32x4;

// ---------- quantization: nearest of {0,±1,±.5,±.333333,±.2,±.142857,±.090909,±.076923} ----------
// Tie-break matches the reference's first-min scan over the LUT:
//   boundary to 0 (index 0 seen first)          -> strict >
//   boundaries between nonzero magnitudes (larger magnitude = lower index) -> >=
__device__ __forceinline__ float quantize1(float w, float scale) {
    float ws = w / scale;
    float a  = fabsf(ws);
    float v  = 0.0f;
    v = (a >  0.0384615f) ? 0.076923f : v;
    v = (a >= 0.0839160f) ? 0.090909f : v;
    v = (a >= 0.1168830f) ? 0.142857f : v;
    v = (a >= 0.1714285f) ? 0.2f      : v;
    v = (a >= 0.2666665f) ? 0.333333f : v;
    v = (a >= 0.4166665f) ? 0.5f      : v;
    v = (a >= 0.75f)      ? 1.0f      : v;
    v = copysignf(v, ws);
    return v * scale;
}

__device__ __forceinline__ unsigned short to_bf16(float f) {
    unsigned int u = __float_as_uint(f);
    u += 0x7FFFu + ((u >> 16) & 1u);   // RNE
    return (unsigned short)(u >> 16);
}

// ---------- pass 1a: quantize W (fp32) -> bf16 in d_ws ----------
__global__ void quant_w_kernel(const float* __restrict__ W,
                               const float* __restrict__ scale_p,
                               unsigned short* __restrict__ Wq, int n4) {
    const float s = scale_p[0];
    int idx    = blockIdx.x * blockDim.x + threadIdx.x;
    int stride = gridDim.x * blockDim.x;
    const float4* W4 = (const float4*)W;
    ushort4* Q4 = (ushort4*)Wq;
    for (int i = idx; i < n4; i += stride) {
        float4 w = W4[i];
        ushort4 q;
        q.x = to_bf16(quantize1(w.x, s));
        q.y = to_bf16(quantize1(w.y, s));
        q.z = to_bf16(quantize1(w.z, s));
        q.w = to_bf16(quantize1(w.w, s));
        Q4[i] = q;
    }
}

// ---------- pass 1b: convert x (fp32) -> bf16 in d_ws ----------
__global__ void conv_x_kernel(const float* __restrict__ X,
                              unsigned short* __restrict__ Xb, int n4) {
    int idx    = blockIdx.x * blockDim.x + threadIdx.x;
    int stride = gridDim.x * blockDim.x;
    const float4* X4 = (const float4*)X;
    ushort4* Q4 = (ushort4*)Xb;
    for (int i = idx; i < n4; i += stride) {
        float4 w = X4[i];
        ushort4 q;
        q.x = to_bf16(w.x); q.y = to_bf16(w.y);
        q.z = to_bf16(w.z); q.w = to_bf16(w.w);
        Q4[i] = q;
    }
}

// ---------- pass 2: bf16 GEMM, C[M,N] = A[M,K] * B[N,K]^T  (m97 structure) ----------
// 256 threads = 4 waves (2x2), tile 128x128, BK=32, 16x16x32 MFMA, async global->LDS 16B.
__global__ __launch_bounds__(256) void gemm_bt_bf16(
        const unsigned short* __restrict__ A,   // [M][K] bf16 bits
        const unsigned short* __restrict__ B,   // [N][K] bf16 bits
        float* __restrict__ C, int M) {
    __shared__ unsigned short sA[128 * 32];     // row-major [m][k], 64 B rows
    __shared__ unsigned short sB[128 * 32];

    const int tid  = threadIdx.x;
    const int w    = tid >> 6;
    const int lane = tid & 63;
    const int quad = lane >> 4;
    const int l16  = lane & 15;
    const int wm   = w >> 1;                    // 2x2 wave grid
    const int wn   = w & 1;

    const int ntile = blockIdx.x & 63;          // N/128 = 64
    const int mtile = blockIdx.x >> 6;
    const int m0 = mtile * 128;
    const int n0 = ntile * 128;

    f32x4 acc[4][4];
    const f32x4 z = {0.f, 0.f, 0.f, 0.f};
#pragma unroll
    for (int i = 0; i < 4; ++i)
#pragma unroll
        for (int j = 0; j < 4; ++j) acc[i][j] = z;

    const char* Abase = (const char*)A;
    const char* Bbase = (const char*)B;
    char* sAb = (char*)sA;
    char* sBb = (char*)sB;

    for (int k0 = 0; k0 < K_DIM; k0 += 32) {
        // stage A (8 KB) + B (8 KB): 2 passes each, 16 B per lane per pass.
        // HW writes LDS at (wave-uniform base) + lane*16, so chunk c = p*256+tid
        // lands at byte c*16 -> row-major [row=c>>2][kchunk=c&3].
#pragma unroll
        for (int p = 0; p < 2; ++p) {
            int c   = p * 256 + tid;
            int row = c >> 2;
            int kc  = c & 3;
            const char* ga = Abase + ((size_t)(m0 + row) * K_DIM + k0) * 2 + kc * 16;
            const char* gb = Bbase + ((size_t)(n0 + row) * K_DIM + k0) * 2 + kc * 16;
            char* la = sAb + p * 4096 + w * 1024;
            char* lb = sBb + p * 4096 + w * 1024;
            __builtin_amdgcn_global_load_lds((const __attribute__((address_space(1))) void*)ga,
                                             (__attribute__((address_space(3))) void*)la, 16, 0, 0);
            __builtin_amdgcn_global_load_lds((const __attribute__((address_space(1))) void*)gb,
                                             (__attribute__((address_space(3))) void*)lb, 16, 0, 0);
        }
        __syncthreads();

        bf16x8 af[4], bf[4];
#pragma unroll
        for (int i = 0; i < 4; ++i) {
            af[i] = *(const bf16x8*)(sAb + ((size_t)(wm * 64 + i * 16 + l16) * 32 + quad * 8) * 2);
            bf[i] = *(const bf16x8*)(sBb + ((size_t)(wn * 64 + i * 16 + l16) * 32 + quad * 8) * 2);
        }
#pragma unroll
        for (int mi = 0; mi < 4; ++mi)
#pragma unroll
            for (int ni = 0; ni < 4; ++ni)
                acc[mi][ni] = __builtin_amdgcn_mfma_f32_16x16x32_bf16(af[mi], bf[ni], acc[mi][ni], 0, 0, 0);
        __syncthreads();
    }

    // epilogue: D row = m (quad*4+reg), col = n (lane&15)  [verified mapping, m89/m91]
#pragma unroll
    for (int mi = 0; mi < 4; ++mi) {
#pragma unroll
        for (int ni = 0; ni < 4; ++ni) {
            int row = m0 + wm * 64 + mi * 16 + quad * 4;
            int col = n0 + wn * 64 + ni * 16 + l16;
#pragma unroll
            for (int r = 0; r < 4; ++r)
                C[(size_t)(row + r) * N_DIM + col] = acc[mi][ni][r];
        }
    }
}

// ---------- fallback (ws too small): quantize W in place (fp32), fp32 tiled GEMM ----------
__global__ void quant_w_inplace(float* W, const float* __restrict__ scale_p, int n4) {
    const float s = scale_p[0];
    int idx    = blockIdx.x * blockDim.x + threadIdx.x;
    int stride = gridDim.x * blockDim.x;
    float4* W4 = (float4*)W;
    for (int i = idx; i < n4; i += stride) {
        float4 w = W4[i];
        w.x = quantize1(w.x, s); w.y = quantize1(w.y, s);
        w.z = quantize1(w.z, s); w.w = quantize1(w.w, s);
        W4[i] = w;
    }
}

__global__ __launch_bounds__(256) void gemm_fp32_fb(const float* __restrict__ A,
                                                    const float* __restrict__ B,
                                                    float* __restrict__ C, int M) {
    __shared__ float sA[64][17];
    __shared__ float sB[64][17];
    int tid = threadIdx.x;
    int tx = tid & 15, ty = tid >> 4;
    int n0 = (blockIdx.x & 127) * 64;          // N/64 = 128
    int m0 = (blockIdx.x >> 7) * 64;
    float acc[4][4] = {};
    for (int k0 = 0; k0 < K_DIM; k0 += 16) {
#pragma unroll
        for (int i = 0; i < 4; ++i) {
            int e = tid + i * 256;
            int r = e >> 4, c = e & 15;
            sA[r][c] = A[(size_t)(m0 + r) * K_DIM + k0 + c];
            sB[r][c] = B[(size_t)(n0 + r) * K_DIM + k0 + c];
        }
        __syncthreads();
#pragma unroll
        for (int kk = 0; kk < 16; ++kk) {
            float a[4], b[4];
#pragma unroll
            for (int i = 0; i < 4; ++i) { a[i] = sA[ty * 4 + i][kk]; b[i] = sB[tx * 4 + i][kk]; }
#pragma unroll
            for (int i = 0; i < 4; ++i)
#pragma unroll
                for (int j = 0; j < 4; ++j) acc[i][j] += a[i] * b[j];
        }
        __syncthreads();
    }
#pragma unroll
    for (int i = 0; i < 4; ++i)
#pragma unroll
        for (int j = 0; j < 4; ++j)
            C[(size_t)(m0 + ty * 4 + i) * N_DIM + n0 + tx * 4 + j] = acc[i][j];
}

extern "C" void kernel_launch(void* const* d_in, const int* in_sizes, int n_in,
                              void* d_out, int out_size, void* d_ws, size_t ws_size,
                              hipStream_t stream) {
    const float* x     = (const float*)d_in[0];
    const float* W     = (const float*)d_in[1];
    const float* scale = (const float*)d_in[2];
    float* out = (float*)d_out;

    const int M = in_sizes[0] / K_DIM;                       // 1024
    const size_t wq_bytes = (size_t)N_DIM * K_DIM * 2;       // 64 MiB
    const size_t xb_bytes = (size_t)M * K_DIM * 2;           // 8 MiB

    if (ws_size >= wq_bytes + xb_bytes && (M % 128) == 0) {
        unsigned short* Wq = (unsigned short*)d_ws;
        unsigned short* Xb = (unsigned short*)((char*)d_ws + wq_bytes);
        int nW4 = (N_DIM * K_DIM) / 4;
        int nX4 = (M * K_DIM) / 4;
        hipLaunchKernelGGL(quant_w_kernel, dim3(2048), dim3(256), 0, stream, W, scale, Wq, nW4);
        hipLaunchKernelGGL(conv_x_kernel, dim3(1024), dim3(256), 0, stream, x, Xb, nX4);
        hipLaunchKernelGGL(gemm_bt_bf16, dim3((M / 128) * (N_DIM / 128)), dim3(256), 0, stream,
                           Xb, Wq, out, M);
    } else {
        int nW4 = (N_DIM * K_DIM) / 4;
        hipLaunchKernelGGL(quant_w_inplace, dim3(2048), dim3(256), 0, stream,
                           (float*)W, scale, nW4);
        hipLaunchKernelGGL(gemm_fp32_fb, dim3((M / 64) * (N_DIM / 64)), dim3(256), 0, stream,
                           x, W, out, M);
    }
}

// Round 2
// 309.379 us; speedup vs baseline: 1.0138x; 1.0138x over previous
//
#include <hip/hip_runtime.h>
#include <hip/hip_bf16.h>
#include <stdint.h>

#define K_DIM 4096
#define N_DIM 8192

typedef __attribute__((ext_vector_type(8))) __bf16 bf16x8;
typedef __attribute__((ext_vector_type(4))) float f32x4;

// ---------- quantization: nearest of {0,±1,±.5,±.333333,±.2,±.142857,±.090909,±.076923} ----------
// Tie-break matches the reference's first-min scan over the LUT:
//   boundary to 0 (index 0 seen first)          -> strict >
//   boundaries between nonzero magnitudes (larger magnitude = lower index) -> >=
__device__ __forceinline__ float quantize1(float w, float scale) {
    float ws = w / scale;
    float a  = fabsf(ws);
    float v  = 0.0f;
    v = (a >  0.0384615f) ? 0.076923f : v;
    v = (a >= 0.0839160f) ? 0.090909f : v;
    v = (a >= 0.1168830f) ? 0.142857f : v;
    v = (a >= 0.1714285f) ? 0.2f      : v;
    v = (a >= 0.2666665f) ? 0.333333f : v;
    v = (a >= 0.4166665f) ? 0.5f      : v;
    v = (a >= 0.75f)      ? 1.0f      : v;
    v = copysignf(v, ws);
    return v * scale;
}

__device__ __forceinline__ unsigned short to_bf16(float f) {
    unsigned int u = __float_as_uint(f);
    u += 0x7FFFu + ((u >> 16) & 1u);   // RNE
    return (unsigned short)(u >> 16);
}

// ---------- pass 1a: quantize W (fp32) -> bf16 in d_ws ----------
__global__ void quant_w_kernel(const float* __restrict__ W,
                               const float* __restrict__ scale_p,
                               unsigned short* __restrict__ Wq, int n4) {
    const float s = scale_p[0];
    int idx    = blockIdx.x * blockDim.x + threadIdx.x;
    int stride = gridDim.x * blockDim.x;
    const float4* W4 = (const float4*)W;
    ushort4* Q4 = (ushort4*)Wq;
    for (int i = idx; i < n4; i += stride) {
        float4 w = W4[i];
        ushort4 q;
        q.x = to_bf16(quantize1(w.x, s));
        q.y = to_bf16(quantize1(w.y, s));
        q.z = to_bf16(quantize1(w.z, s));
        q.w = to_bf16(quantize1(w.w, s));
        Q4[i] = q;
    }
}

// ---------- pass 1b: convert x (fp32) -> bf16 in d_ws ----------
__global__ void conv_x_kernel(const float* __restrict__ X,
                              unsigned short* __restrict__ Xb, int n4) {
    int idx    = blockIdx.x * blockDim.x + threadIdx.x;
    int stride = gridDim.x * blockDim.x;
    const float4* X4 = (const float4*)X;
    ushort4* Q4 = (ushort4*)Xb;
    for (int i = idx; i < n4; i += stride) {
        float4 w = X4[i];
        ushort4 q;
        q.x = to_bf16(w.x); q.y = to_bf16(w.y);
        q.z = to_bf16(w.z); q.w = to_bf16(w.w);
        Q4[i] = q;
    }
}

// ---------- pass 2: bf16 GEMM, C[M,N] = A[M,K] * B[N,K]^T ----------
// Tile 64x128 (grid 16x64 = 1024 blocks -> 4 blocks/CU for latency hiding;
// the 128x128 version gave only 512 blocks = 2/CU, Occupancy 20%, MfmaUtil 26%).
// 256 threads = 4 waves in 1x4 over N; each wave computes 64x32 via 4x2 MFMA frags.
// Per-output K-accumulation order identical to the 128x128 version (bit-exact).
__global__ __launch_bounds__(256) void gemm_bt_bf16(
        const unsigned short* __restrict__ A,   // [M][K] bf16 bits
        const unsigned short* __restrict__ B,   // [N][K] bf16 bits
        float* __restrict__ C, int M) {
    __shared__ unsigned short sA[64 * 32];      // row-major [m][k], 64 B rows (4 KB)
    __shared__ unsigned short sB[128 * 32];     // row-major [n][k] (8 KB)

    const int tid  = threadIdx.x;
    const int w    = tid >> 6;                  // wave 0..3 -> N window w*32
    const int lane = tid & 63;
    const int quad = lane >> 4;
    const int l16  = lane & 15;

    const int ntile = blockIdx.x & 63;          // N/128 = 64
    const int mtile = blockIdx.x >> 6;          // M/64 = 16
    const int m0 = mtile * 64;
    const int n0 = ntile * 128;

    f32x4 acc[4][2];
    const f32x4 z = {0.f, 0.f, 0.f, 0.f};
#pragma unroll
    for (int i = 0; i < 4; ++i)
#pragma unroll
        for (int j = 0; j < 2; ++j) acc[i][j] = z;

    const char* Abase = (const char*)A;
    const char* Bbase = (const char*)B;
    char* sAb = (char*)sA;
    char* sBb = (char*)sB;

    for (int k0 = 0; k0 < K_DIM; k0 += 32) {
        // stage A (4 KB, 1 chunk/thread) + B (8 KB, 2 chunks/thread), 16 B chunks.
        // HW writes LDS at (wave-uniform base) + lane*16; chunk c lands at byte
        // c*16 -> row-major [row=c>>2][kchunk=c&3].
        {
            int row = tid >> 2;
            int kc  = tid & 3;
            const char* ga = Abase + ((size_t)(m0 + row) * K_DIM + k0) * 2 + kc * 16;
            char* la = sAb + w * 1024;
            __builtin_amdgcn_global_load_lds((const __attribute__((address_space(1))) void*)ga,
                                             (__attribute__((address_space(3))) void*)la, 16, 0, 0);
        }
#pragma unroll
        for (int p = 0; p < 2; ++p) {
            int c   = p * 256 + tid;
            int row = c >> 2;
            int kc  = c & 3;
            const char* gb = Bbase + ((size_t)(n0 + row) * K_DIM + k0) * 2 + kc * 16;
            char* lb = sBb + p * 4096 + w * 1024;
            __builtin_amdgcn_global_load_lds((const __attribute__((address_space(1))) void*)gb,
                                             (__attribute__((address_space(3))) void*)lb, 16, 0, 0);
        }
        __syncthreads();

        bf16x8 af[4], bf[2];
#pragma unroll
        for (int i = 0; i < 4; ++i)
            af[i] = *(const bf16x8*)(sAb + ((size_t)(i * 16 + l16) * 32 + quad * 8) * 2);
#pragma unroll
        for (int j = 0; j < 2; ++j)
            bf[j] = *(const bf16x8*)(sBb + ((size_t)(w * 32 + j * 16 + l16) * 32 + quad * 8) * 2);
#pragma unroll
        for (int mi = 0; mi < 4; ++mi)
#pragma unroll
            for (int ni = 0; ni < 2; ++ni)
                acc[mi][ni] = __builtin_amdgcn_mfma_f32_16x16x32_bf16(af[mi], bf[ni], acc[mi][ni], 0, 0, 0);
        __syncthreads();
    }

    // epilogue: D row = m (quad*4+reg), col = n (lane&15)  [verified mapping, m89/m91]
#pragma unroll
    for (int mi = 0; mi < 4; ++mi) {
#pragma unroll
        for (int ni = 0; ni < 2; ++ni) {
            int row = m0 + mi * 16 + quad * 4;
            int col = n0 + w * 32 + ni * 16 + l16;
#pragma unroll
            for (int r = 0; r < 4; ++r)
                C[(size_t)(row + r) * N_DIM + col] = acc[mi][ni][r];
        }
    }
}

// ---------- fallback (ws too small): quantize W in place (fp32), fp32 tiled GEMM ----------
__global__ void quant_w_inplace(float* W, const float* __restrict__ scale_p, int n4) {
    const float s = scale_p[0];
    int idx    = blockIdx.x * blockDim.x + threadIdx.x;
    int stride = gridDim.x * blockDim.x;
    float4* W4 = (float4*)W;
    for (int i = idx; i < n4; i += stride) {
        float4 w = W4[i];
        w.x = quantize1(w.x, s); w.y = quantize1(w.y, s);
        w.z = quantize1(w.z, s); w.w = quantize1(w.w, s);
        W4[i] = w;
    }
}

__global__ __launch_bounds__(256) void gemm_fp32_fb(const float* __restrict__ A,
                                                    const float* __restrict__ B,
                                                    float* __restrict__ C, int M) {
    __shared__ float sA[64][17];
    __shared__ float sB[64][17];
    int tid = threadIdx.x;
    int tx = tid & 15, ty = tid >> 4;
    int n0 = (blockIdx.x & 127) * 64;          // N/64 = 128
    int m0 = (blockIdx.x >> 7) * 64;
    float acc[4][4] = {};
    for (int k0 = 0; k0 < K_DIM; k0 += 16) {
#pragma unroll
        for (int i = 0; i < 4; ++i) {
            int e = tid + i * 256;
            int r = e >> 4, c = e & 15;
            sA[r][c] = A[(size_t)(m0 + r) * K_DIM + k0 + c];
            sB[r][c] = B[(size_t)(n0 + r) * K_DIM + k0 + c];
        }
        __syncthreads();
#pragma unroll
        for (int kk = 0; kk < 16; ++kk) {
            float a[4], b[4];
#pragma unroll
            for (int i = 0; i < 4; ++i) { a[i] = sA[ty * 4 + i][kk]; b[i] = sB[tx * 4 + i][kk]; }
#pragma unroll
            for (int i = 0; i < 4; ++i)
#pragma unroll
                for (int j = 0; j < 4; ++j) acc[i][j] += a[i] * b[j];
        }
        __syncthreads();
    }
#pragma unroll
    for (int i = 0; i < 4; ++i)
#pragma unroll
        for (int j = 0; j < 4; ++j)
            C[(size_t)(m0 + ty * 4 + i) * N_DIM + n0 + tx * 4 + j] = acc[i][j];
}

extern "C" void kernel_launch(void* const* d_in, const int* in_sizes, int n_in,
                              void* d_out, int out_size, void* d_ws, size_t ws_size,
                              hipStream_t stream) {
    const float* x     = (const float*)d_in[0];
    const float* W     = (const float*)d_in[1];
    const float* scale = (const float*)d_in[2];
    float* out = (float*)d_out;

    const int M = in_sizes[0] / K_DIM;                       // 1024
    const size_t wq_bytes = (size_t)N_DIM * K_DIM * 2;       // 64 MiB
    const size_t xb_bytes = (size_t)M * K_DIM * 2;           // 8 MiB

    if (ws_size >= wq_bytes + xb_bytes && (M % 64) == 0) {
        unsigned short* Wq = (unsigned short*)d_ws;
        unsigned short* Xb = (unsigned short*)((char*)d_ws + wq_bytes);
        int nW4 = (N_DIM * K_DIM) / 4;
        int nX4 = (M * K_DIM) / 4;
        hipLaunchKernelGGL(quant_w_kernel, dim3(2048), dim3(256), 0, stream, W, scale, Wq, nW4);
        hipLaunchKernelGGL(conv_x_kernel, dim3(1024), dim3(256), 0, stream, x, Xb, nX4);
        hipLaunchKernelGGL(gemm_bt_bf16, dim3((M / 64) * (N_DIM / 128)), dim3(256), 0, stream,
                           Xb, Wq, out, M);
    } else {
        int nW4 = (N_DIM * K_DIM) / 4;
        hipLaunchKernelGGL(quant_w_inplace, dim3(2048), dim3(256), 0, stream,
                           (float*)W, scale, nW4);
        hipLaunchKernelGGL(gemm_fp32_fb, dim3((M / 64) * (N_DIM / 64)), dim3(256), 0, stream,
                           x, W, out, M);
    }
}